// Round 1
// baseline (343.564 us; speedup 1.0000x reference)
//
#include <hip/hip_runtime.h>

#define NB 8
#define NS 2048
#define ND 64
#define TQ 32
#define TK 64
#define SP 68   // padded LDS stride (floats): 68*4B is 16B-aligned, odd*4 bank step

// ---------------- QKV projection ----------------
// grid: B*N/64 blocks of 256 threads. Each block: 64 rows of x.
// W columns cached in registers (fixed col per thread), x rows broadcast from LDS.
__global__ __launch_bounds__(256) void qkv_proj(
    const float* __restrict__ x,
    const float* __restrict__ Wq, const float* __restrict__ bq,
    const float* __restrict__ Wk, const float* __restrict__ bk,
    const float* __restrict__ Wv, const float* __restrict__ bv,
    float* __restrict__ Q, float* __restrict__ K, float* __restrict__ V)
{
    __shared__ float xs[64 * 64];
    const int tid = threadIdx.x;
    const size_t base = (size_t)blockIdx.x * (64 * 64);

    const float4* xg = (const float4*)(x + base);
    float4* xs4 = (float4*)xs;
#pragma unroll
    for (int j = 0; j < 4; ++j) xs4[j * 256 + tid] = xg[j * 256 + tid];
    __syncthreads();

    const int c  = tid & 63;
    const int rg = tid >> 6;   // 0..3 -> 16 rows each
    const float* Ws[3] = {Wq, Wk, Wv};
    const float* Bs[3] = {bq, bk, bv};
    float*       Os[3] = {Q, K, V};

    for (int m = 0; m < 3; ++m) {
        float wcol[64];
#pragma unroll
        for (int d = 0; d < 64; ++d) wcol[d] = Ws[m][d * 64 + c];
        const float bias = Bs[m][c];
        for (int rr = 0; rr < 16; ++rr) {
            const int r = rg * 16 + rr;
            const float* xr = xs + r * 64;
            float acc = bias;
#pragma unroll
            for (int d = 0; d < 64; ++d) acc += xr[d] * wcol[d];
            Os[m][base + (size_t)r * 64 + c] = acc;
        }
    }
}

// ---------------- fused two-pass masked attention ----------------
// grid: (N/TQ, B) blocks of 256 threads. Block handles 32 query rows vs all keys.
// Thread tile: 2 q-rows x 4 k-cols (scores) / 2 q-rows x 4 dims (PV).
__global__ __launch_bounds__(256) void attn(
    const float* __restrict__ Q, const float* __restrict__ K,
    const float* __restrict__ V, float* __restrict__ out)
{
    __shared__ float qs[TQ * SP];   // [r][d]
    __shared__ float kts[ND * SP];  // transposed: [d][c]
    __shared__ float vs[TK * SP];   // [c][d]
    __shared__ float ps[TQ * SP];   // sparse probs [r][k]

    const int tid = threadIdx.x;
    const int b  = blockIdx.y;
    const int q0 = blockIdx.x * TQ;
    const float* Qb = Q + ((size_t)b * NS + q0) * ND;
    const float* Kb = K + (size_t)b * NS * ND;
    const float* Vb = V + (size_t)b * NS * ND;

    // load Q tile (coalesced float4)
#pragma unroll
    for (int j = 0; j < 2; ++j) {
        int f = tid + j * 256;          // 512 float4s
        int r = f >> 4;
        int dbase = (f & 15) << 2;
        *(float4*)(qs + r * SP + dbase) = *(const float4*)(Qb + (size_t)r * ND + dbase);
    }

    const int tx = tid & 15;
    const int ty = tid >> 4;
    const int r0 = 2 * ty, r1 = 2 * ty + 1;
    const int c0 = 4 * tx;

    float m0 = -1e30f, l0 = 0.f, m1 = -1e30f, l1 = 0.f;

    // ---- pass 1: row max + denom (online) ----
    for (int kc = 0; kc < NS / TK; ++kc) {
        __syncthreads();
        const float* Kc = Kb + (size_t)kc * TK * ND;
#pragma unroll
        for (int j = 0; j < 4; ++j) {
            int f = tid + j * 256;
            int cc = f >> 4;
            int dbase = (f & 15) << 2;
            float4 v = *(const float4*)(Kc + (size_t)cc * ND + dbase);
            kts[(dbase + 0) * SP + cc] = v.x;
            kts[(dbase + 1) * SP + cc] = v.y;
            kts[(dbase + 2) * SP + cc] = v.z;
            kts[(dbase + 3) * SP + cc] = v.w;
        }
        __syncthreads();

        float s00=0,s01=0,s02=0,s03=0,s10=0,s11=0,s12=0,s13=0;
#pragma unroll 16
        for (int d = 0; d < ND; ++d) {
            float qa = qs[r0 * SP + d];
            float qb = qs[r1 * SP + d];
            float4 kv = *(const float4*)(kts + d * SP + c0);
            s00 += qa * kv.x; s01 += qa * kv.y; s02 += qa * kv.z; s03 += qa * kv.w;
            s10 += qb * kv.x; s11 += qb * kv.y; s12 += qb * kv.z; s13 += qb * kv.w;
        }
        float mc0 = fmaxf(fmaxf(s00, s01), fmaxf(s02, s03));
        float mn0 = fmaxf(m0, mc0);
        l0 = l0 * __expf(m0 - mn0)
           + __expf(s00 - mn0) + __expf(s01 - mn0) + __expf(s02 - mn0) + __expf(s03 - mn0);
        m0 = mn0;
        float mc1 = fmaxf(fmaxf(s10, s11), fmaxf(s12, s13));
        float mn1 = fmaxf(m1, mc1);
        l1 = l1 * __expf(m1 - mn1)
           + __expf(s10 - mn1) + __expf(s11 - mn1) + __expf(s12 - mn1) + __expf(s13 - mn1);
        m1 = mn1;
    }

    // butterfly reduce (m,l) across the 16 lanes sharing the same rows
#pragma unroll
    for (int off = 1; off < 16; off <<= 1) {
        float mo = __shfl_xor(m0, off);
        float lo = __shfl_xor(l0, off);
        float mn = fmaxf(m0, mo);
        l0 = l0 * __expf(m0 - mn) + lo * __expf(mo - mn);
        m0 = mn;
        mo = __shfl_xor(m1, off);
        lo = __shfl_xor(l1, off);
        mn = fmaxf(m1, mo);
        l1 = l1 * __expf(m1 - mn) + lo * __expf(mo - mn);
        m1 = mn;
    }
    const float inv0 = 1.f / l0, th0 = l0 * (1.f / NS);  // keep iff exp(s-m) > l/N  <=>  p > 1/N
    const float inv1 = 1.f / l1, th1 = l1 * (1.f / NS);

    float4 o0 = {0.f, 0.f, 0.f, 0.f}, o1 = {0.f, 0.f, 0.f, 0.f};

    // ---- pass 2: recompute scores, threshold, accumulate PV ----
    for (int kc = 0; kc < NS / TK; ++kc) {
        __syncthreads();
        const float* Kc = Kb + (size_t)kc * TK * ND;
        const float* Vc = Vb + (size_t)kc * TK * ND;
#pragma unroll
        for (int j = 0; j < 4; ++j) {
            int f = tid + j * 256;
            int cc = f >> 4;
            int dbase = (f & 15) << 2;
            float4 v = *(const float4*)(Kc + (size_t)cc * ND + dbase);
            kts[(dbase + 0) * SP + cc] = v.x;
            kts[(dbase + 1) * SP + cc] = v.y;
            kts[(dbase + 2) * SP + cc] = v.z;
            kts[(dbase + 3) * SP + cc] = v.w;
            *(float4*)(vs + cc * SP + dbase) = *(const float4*)(Vc + (size_t)cc * ND + dbase);
        }
        __syncthreads();

        float s00=0,s01=0,s02=0,s03=0,s10=0,s11=0,s12=0,s13=0;
#pragma unroll 16
        for (int d = 0; d < ND; ++d) {
            float qa = qs[r0 * SP + d];
            float qb = qs[r1 * SP + d];
            float4 kv = *(const float4*)(kts + d * SP + c0);
            s00 += qa * kv.x; s01 += qa * kv.y; s02 += qa * kv.z; s03 += qa * kv.w;
            s10 += qb * kv.x; s11 += qb * kv.y; s12 += qb * kv.z; s13 += qb * kv.w;
        }
        float4 w0, w1;
        float e;
        e = __expf(s00 - m0); w0.x = (e > th0) ? e * inv0 : 0.f;
        e = __expf(s01 - m0); w0.y = (e > th0) ? e * inv0 : 0.f;
        e = __expf(s02 - m0); w0.z = (e > th0) ? e * inv0 : 0.f;
        e = __expf(s03 - m0); w0.w = (e > th0) ? e * inv0 : 0.f;
        e = __expf(s10 - m1); w1.x = (e > th1) ? e * inv1 : 0.f;
        e = __expf(s11 - m1); w1.y = (e > th1) ? e * inv1 : 0.f;
        e = __expf(s12 - m1); w1.z = (e > th1) ? e * inv1 : 0.f;
        e = __expf(s13 - m1); w1.w = (e > th1) ? e * inv1 : 0.f;
        *(float4*)(ps + r0 * SP + c0) = w0;
        *(float4*)(ps + r1 * SP + c0) = w1;
        __syncthreads();

#pragma unroll 16
        for (int k = 0; k < TK; ++k) {
            float p0 = ps[r0 * SP + k];
            float p1 = ps[r1 * SP + k];
            float4 vv = *(const float4*)(vs + k * SP + c0);
            o0.x += p0 * vv.x; o0.y += p0 * vv.y; o0.z += p0 * vv.z; o0.w += p0 * vv.w;
            o1.x += p1 * vv.x; o1.y += p1 * vv.y; o1.z += p1 * vv.z; o1.w += p1 * vv.w;
        }
    }

    float* ob = out + ((size_t)b * NS + q0) * ND;
    *(float4*)(ob + (size_t)r0 * ND + c0) = o0;
    *(float4*)(ob + (size_t)r1 * ND + c0) = o1;
}

extern "C" void kernel_launch(void* const* d_in, const int* in_sizes, int n_in,
                              void* d_out, int out_size, void* d_ws, size_t ws_size,
                              hipStream_t stream) {
    const float* x  = (const float*)d_in[0];
    const float* Wq = (const float*)d_in[1];
    const float* bq = (const float*)d_in[2];
    const float* Wk = (const float*)d_in[3];
    const float* bk = (const float*)d_in[4];
    const float* Wv = (const float*)d_in[5];
    const float* bv = (const float*)d_in[6];

    float* ws = (float*)d_ws;
    const size_t QKV = (size_t)NB * NS * ND;   // 1,048,576 floats each
    float* Q = ws;
    float* K = ws + QKV;
    float* V = ws + 2 * QKV;

    qkv_proj<<<(NB * NS) / 64, 256, 0, stream>>>(x, Wq, bq, Wk, bk, Wv, bv, Q, K, V);
    attn<<<dim3(NS / TQ, NB), 256, 0, stream>>>(Q, K, V, (float*)d_out);
}

// Round 3
// 164.214 us; speedup vs baseline: 2.0922x; 2.0922x over previous
//
#include <hip/hip_runtime.h>

#define NB 8
#define NS 2048
#define ND 64

typedef _Float16 half8 __attribute__((ext_vector_type(8)));
typedef __attribute__((ext_vector_type(4))) float floatx4;

// ---------------- QKV projection: fp32 compute, fp16 out (Q,K row-major; V transposed) ----
__global__ __launch_bounds__(256) void qkv_proj(
    const float* __restrict__ x,
    const float* __restrict__ Wq, const float* __restrict__ bq,
    const float* __restrict__ Wk, const float* __restrict__ bk,
    const float* __restrict__ Wv, const float* __restrict__ bv,
    _Float16* __restrict__ Qg, _Float16* __restrict__ Kg,
    _Float16* __restrict__ Vt)
{
    __shared__ float xs_t[64 * 68];      // [d][r], pad 68
    __shared__ float wls[64 * 68];       // [d][c], one matrix at a time
    __shared__ _Float16 vt[64 * 72];     // [c][r] fp16, pad 72 (16B-aligned rows)

    const int tid = threadIdx.x;
    const int b  = blockIdx.x >> 5;      // 32 row-tiles per batch
    const int nb = blockIdx.x & 31;
    const int n0 = nb * 64;
    const size_t xbase = ((size_t)b * NS + n0) * ND;

    // stage x tile TRANSPOSED: wave w covers dims 16w..16w+15, lane = row
    {
        const int r = tid & 63;
        const int dbase = (tid >> 6) * 16;
#pragma unroll
        for (int j = 0; j < 4; ++j) {
            float4 v = *(const float4*)(x + xbase + (size_t)r * ND + dbase + j * 4);
            xs_t[(dbase + j * 4 + 0) * 68 + r] = v.x;
            xs_t[(dbase + j * 4 + 1) * 68 + r] = v.y;
            xs_t[(dbase + j * 4 + 2) * 68 + r] = v.z;
            xs_t[(dbase + j * 4 + 3) * 68 + r] = v.w;
        }
    }

    const float* Ws[3] = {Wq, Wk, Wv};
    const float* Bs[3] = {bq, bk, bv};
    const int r0 = (tid >> 4) * 4;
    const int c0 = (tid & 15) * 4;

    for (int m = 0; m < 3; ++m) {
        __syncthreads();   // covers xs_t staging (m=0) and wls reuse (m>0)
#pragma unroll
        for (int j = 0; j < 4; ++j) {
            int f = tid + j * 256;
            int d = f >> 4, cc = (f & 15) * 4;
            *(float4*)&wls[d * 68 + cc] = *(const float4*)(Ws[m] + d * 64 + cc);
        }
        __syncthreads();

        float4 b4 = *(const float4*)(Bs[m] + c0);
        float acc[4][4];
#pragma unroll
        for (int i = 0; i < 4; ++i) {
            acc[i][0] = b4.x; acc[i][1] = b4.y; acc[i][2] = b4.z; acc[i][3] = b4.w;
        }
        for (int d = 0; d < 64; ++d) {
            float4 w4 = *(float4*)&wls[d * 68 + c0];
            float4 x4 = *(float4*)&xs_t[d * 68 + r0];
            float wr[4] = {w4.x, w4.y, w4.z, w4.w};
            float xr[4] = {x4.x, x4.y, x4.z, x4.w};
#pragma unroll
            for (int i = 0; i < 4; ++i)
#pragma unroll
                for (int j = 0; j < 4; ++j)
                    acc[i][j] += xr[i] * wr[j];
        }

        if (m < 2) {
            _Float16* O = (m == 0) ? Qg : Kg;
#pragma unroll
            for (int i = 0; i < 4; ++i) {
                _Float16 u[4] = {(_Float16)acc[i][0], (_Float16)acc[i][1],
                                 (_Float16)acc[i][2], (_Float16)acc[i][3]};
                *(ushort4*)(O + ((size_t)b * NS + n0 + r0 + i) * ND + c0) = *(ushort4*)u;
            }
        } else {
            // V: transpose in LDS, store Vt[b][d][n] row-major
#pragma unroll
            for (int i = 0; i < 4; ++i)
#pragma unroll
                for (int j = 0; j < 4; ++j)
                    vt[(c0 + j) * 72 + r0 + i] = (_Float16)acc[i][j];
            __syncthreads();
            const int d = tid >> 2, seg = tid & 3;
            uint4 p0 = *(uint4*)&vt[d * 72 + seg * 16];
            uint4 p1 = *(uint4*)&vt[d * 72 + seg * 16 + 8];
            _Float16* dst = Vt + ((size_t)b * ND + d) * NS + n0 + seg * 16;
            *(uint4*)(dst + 0) = p0;
            *(uint4*)(dst + 8) = p1;
        }
    }
}

// ---------------- fused two-pass masked attention, fp16 MFMA ----------------
// grid: 1024 blocks (b = blockIdx&7 for XCD L2 locality), 256 threads.
// Block = one 16-row q-tile; 4 waves split the 2048 keys into quarters.
// No LDS staging of K/V (direct global->frag 16B/lane, L1/L2 cached).
__global__ __launch_bounds__(256) void attn(
    const _Float16* __restrict__ Qg,
    const _Float16* __restrict__ Kg,
    const _Float16* __restrict__ Vt,
    float* __restrict__ out)
{
    __shared__ _Float16 pbuf[4 * 16 * 72];  // per-wave P transpose (C->A layout)
    __shared__ float obuf[4 * 16 * 68];     // per-wave partial O
    __shared__ float mlm[64], mll[64];      // per-wave partial (m,l)

    const int tid  = threadIdx.x;
    const int wv   = tid >> 6;
    const int l    = tid & 63;
    const int quad = l >> 4;
    const int tx   = l & 15;

    const int b  = blockIdx.x & 7;
    const int qt = blockIdx.x >> 3;
    const int q0 = qt * 16;

    const _Float16* Qb = Qg + ((size_t)b * NS + q0) * ND;
    const _Float16* Kb = Kg + (size_t)b * NS * ND;
    const _Float16* Vb = Vt + (size_t)b * ND * NS;

    // A-frags for Q (held both passes): lane -> Q[q0+tx][c*32 + quad*8 + j]
    half8 qf0 = *(const half8*)(Qb + (size_t)tx * ND + quad * 8);
    half8 qf1 = *(const half8*)(Qb + (size_t)tx * ND + 32 + quad * 8);

    const floatx4 zf = {0.f, 0.f, 0.f, 0.f};
    const int kstart = wv * (NS / 4);

    // ---- pass 1: per-row max + denom over this wave's key quarter ----
    float mloc[4] = {-1e30f, -1e30f, -1e30f, -1e30f};
    float lloc[4] = {0.f, 0.f, 0.f, 0.f};

    for (int t = 0; t < (NS / 4) / 64; ++t) {
        const int kb = kstart + t * 64;
        floatx4 acc[4];
#pragma unroll
        for (int nt = 0; nt < 4; ++nt) {
            const _Float16* Kr = Kb + (size_t)(kb + nt * 16 + tx) * ND + quad * 8;
            half8 k0 = *(const half8*)(Kr);
            half8 k1 = *(const half8*)(Kr + 32);
            floatx4 c = __builtin_amdgcn_mfma_f32_16x16x32_f16(qf0, k0, zf, 0, 0, 0);
            acc[nt]   = __builtin_amdgcn_mfma_f32_16x16x32_f16(qf1, k1, c, 0, 0, 0);
        }
#pragma unroll
        for (int r = 0; r < 4; ++r) {
            float s0 = acc[0][r], s1 = acc[1][r], s2 = acc[2][r], s3 = acc[3][r];
            float mt = fmaxf(fmaxf(s0, s1), fmaxf(s2, s3));
            float mn = fmaxf(mloc[r], mt);
            lloc[r] = lloc[r] * __expf(mloc[r] - mn)
                    + __expf(s0 - mn) + __expf(s1 - mn) + __expf(s2 - mn) + __expf(s3 - mn);
            mloc[r] = mn;
        }
    }

    // reduce (m,l) across the 16 lanes of each quad (cols)
#pragma unroll
    for (int off = 1; off < 16; off <<= 1) {
#pragma unroll
        for (int r = 0; r < 4; ++r) {
            float mo = __shfl_xor(mloc[r], off);
            float lo = __shfl_xor(lloc[r], off);
            float mn = fmaxf(mloc[r], mo);
            lloc[r] = lloc[r] * __expf(mloc[r] - mn) + lo * __expf(mo - mn);
            mloc[r] = mn;
        }
    }
    if (tx == 0) {
#pragma unroll
        for (int r = 0; r < 4; ++r) {
            mlm[wv * 16 + quad * 4 + r] = mloc[r];
            mll[wv * 16 + quad * 4 + r] = lloc[r];
        }
    }
    __syncthreads();

    // merge across the 4 waves -> final m, 1/l, threshold l/N  (per lane: its quad's 4 rows)
    float mf[4], inv[4], thr[4];
#pragma unroll
    for (int r = 0; r < 4; ++r) {
        const int row = quad * 4 + r;
        float M = -1e30f, L = 0.f;
#pragma unroll
        for (int w = 0; w < 4; ++w) {
            float mm = mlm[w * 16 + row];
            float ll = mll[w * 16 + row];
            float mn = fmaxf(M, mm);
            L = L * __expf(M - mn) + ll * __expf(mm - mn);
            M = mn;
        }
        mf[r] = M;
        inv[r] = 1.f / L;
        thr[r] = L * (1.f / (float)NS);   // keep iff exp(s-m) > l/N  <=>  p > 1/N
    }

    // ---- pass 2: recompute scores, mask+normalize, PV via MFMA ----
    floatx4 o[4] = {zf, zf, zf, zf};
    _Float16* pb = pbuf + wv * (16 * 72);

    for (int t = 0; t < (NS / 4) / 64; ++t) {
        const int kb = kstart + t * 64;
        floatx4 acc[4];
        half8 vf[4][2];
#pragma unroll
        for (int nt = 0; nt < 4; ++nt) {
            const _Float16* Kr = Kb + (size_t)(kb + nt * 16 + tx) * ND + quad * 8;
            half8 k0 = *(const half8*)(Kr);
            half8 k1 = *(const half8*)(Kr + 32);
            floatx4 c = __builtin_amdgcn_mfma_f32_16x16x32_f16(qf0, k0, zf, 0, 0, 0);
            acc[nt]   = __builtin_amdgcn_mfma_f32_16x16x32_f16(qf1, k1, c, 0, 0, 0);
            const _Float16* Vr = Vb + (size_t)(nt * 16 + tx) * NS + kb + quad * 8;
            vf[nt][0] = *(const half8*)(Vr);
            vf[nt][1] = *(const half8*)(Vr + 32);
        }
        // C-layout -> masked prob -> fp16 into per-wave LDS (rows 4q+r, col nt*16+tx)
#pragma unroll
        for (int nt = 0; nt < 4; ++nt) {
#pragma unroll
            for (int r = 0; r < 4; ++r) {
                float e = __expf(acc[nt][r] - mf[r]);
                float w = (e > thr[r]) ? e * inv[r] : 0.f;
                pb[(quad * 4 + r) * 72 + nt * 16 + tx] = (_Float16)w;
            }
        }
        // A-layout read-back + PV MFMA (per-wave, ordered by lgkmcnt; no barrier)
#pragma unroll
        for (int c = 0; c < 2; ++c) {
            half8 af = *(const half8*)(pb + tx * 72 + c * 32 + quad * 8);
#pragma unroll
            for (int nt = 0; nt < 4; ++nt)
                o[nt] = __builtin_amdgcn_mfma_f32_16x16x32_f16(af, vf[nt][c], o[nt], 0, 0, 0);
        }
    }

    // partial O to LDS, cross-wave sum, coalesced store
#pragma unroll
    for (int nt = 0; nt < 4; ++nt)
#pragma unroll
        for (int r = 0; r < 4; ++r)
            obuf[(wv * 16 + quad * 4 + r) * 68 + nt * 16 + tx] = o[nt][r];
    __syncthreads();

    {
        const int row = tid >> 4;
        const int c4 = (tid & 15) * 4;
        float sx = 0.f, sy = 0.f, sz = 0.f, sw = 0.f;
#pragma unroll
        for (int w = 0; w < 4; ++w) {
            float4 v = *(float4*)&obuf[(w * 16 + row) * 68 + c4];
            sx += v.x; sy += v.y; sz += v.z; sw += v.w;
        }
        float4 res = {sx, sy, sz, sw};
        *(float4*)(out + ((size_t)b * NS + q0 + row) * ND + c4) = res;
    }
}

extern "C" void kernel_launch(void* const* d_in, const int* in_sizes, int n_in,
                              void* d_out, int out_size, void* d_ws, size_t ws_size,
                              hipStream_t stream) {
    const float* x  = (const float*)d_in[0];
    const float* Wq = (const float*)d_in[1];
    const float* bq = (const float*)d_in[2];
    const float* Wk = (const float*)d_in[3];
    const float* bk = (const float*)d_in[4];
    const float* Wv = (const float*)d_in[5];
    const float* bv = (const float*)d_in[6];

    _Float16* Qg = (_Float16*)d_ws;
    _Float16* Kg = Qg + (size_t)NB * NS * ND;
    _Float16* Vt = Kg + (size_t)NB * NS * ND;

    qkv_proj<<<NB * (NS / 64), 256, 0, stream>>>(x, Wq, bq, Wk, bk, Wv, bv, Qg, Kg, Vt);
    attn<<<NB * (NS / 16), 256, 0, stream>>>(Qg, Kg, Vt, (float*)d_out);
}